// Round 7
// baseline (273.010 us; speedup 1.0000x reference)
//
#include <hip/hip_runtime.h>

// LinearAttention: x(B,T,D) -> QKV proj -> ELU+1 -> chunked causal linear
// attention -> output proj. B=4 T=4096 D=1024 H=16 HD=64.
// R7: GEMM register-level software pipeline — each phase issues the NEXT
// phase's ds_reads before the current phase's MFMA cluster (av0/av1 per-phase,
// bv0/bv1 per-K-tile double buffers), overlapping the LDS pipe with the
// matrix pipe (R6 serialized them: 620cyc MFMA + 580cyc ds_read per phase).
// Staging ledger/vmcnt(4) placement identical to R4/R6 (conflicts = 0).

typedef __bf16 bf16;
typedef __bf16 bf16x4 __attribute__((ext_vector_type(4)));
typedef __bf16 bf16x8 __attribute__((ext_vector_type(8)));
typedef float f32x4 __attribute__((ext_vector_type(4)));

#define EPS 1e-6f

#define BAR() asm volatile("s_barrier" ::: "memory")
#define VMCNT4() asm volatile("s_waitcnt vmcnt(4)" ::: "memory")
#define VMCNT0() asm volatile("s_waitcnt vmcnt(0)" ::: "memory")

__device__ __forceinline__ void gl_lds16(const void* g, void* l) {
  __builtin_amdgcn_global_load_lds(
      (__attribute__((address_space(1))) void*)g,
      (__attribute__((address_space(3))) void*)l, 16, 0, 0);
}

__device__ __forceinline__ float fmact(float v) {
  return v > 0.f ? v + 1.f : __expf(v);  // elu+1
}

// ------------- prep: x f32->bf16 (blocks 0..8191) + 4x W transpose ----------
__global__ __launch_bounds__(256) void prep(const float* __restrict__ x,
                                            const float* __restrict__ Wq,
                                            const float* __restrict__ Wk,
                                            const float* __restrict__ Wv,
                                            const float* __restrict__ Wo,
                                            bf16* __restrict__ XB,
                                            bf16* __restrict__ WT3,
                                            bf16* __restrict__ WOT) {
  const int bid = blockIdx.x;
  const int t = threadIdx.x;
  if (bid < 8192) {  // x convert: 8192*256*8 = 16,777,216 elems exactly
    size_t base = ((size_t)bid * 256 + t) * 8;
    float4 v0 = *(const float4*)&x[base];
    float4 v1 = *(const float4*)&x[base + 4];
    bf16x8 o;
    o[0] = (bf16)v0.x; o[1] = (bf16)v0.y; o[2] = (bf16)v0.z; o[3] = (bf16)v0.w;
    o[4] = (bf16)v1.x; o[5] = (bf16)v1.y; o[6] = (bf16)v1.z; o[7] = (bf16)v1.w;
    *(bf16x8*)&XB[base] = o;
    return;
  }
  // weight transpose: W (K x N f32) -> WT (N x K bf16), 64x64 tiles
  __shared__ float tile[64][65];
  const int wi = (bid - 8192) >> 8;     // 0..3
  const int local = (bid - 8192) & 255;
  const float* W = (wi == 0) ? Wq : (wi == 1) ? Wk : (wi == 2) ? Wv : Wo;
  bf16* WT = (wi == 3) ? WOT : WT3 + (size_t)wi * 1048576;
  const int k0 = (local & 15) * 64, n0 = (local >> 4) * 64;
  {
    const int r4 = t / 16, c4 = (t % 16) * 4;
#pragma unroll
    for (int rr = 0; rr < 4; ++rr) {
      int r = r4 + rr * 16;
      float4 v = *(const float4*)&W[(size_t)(k0 + r) * 1024 + n0 + c4];
      tile[r][c4] = v.x; tile[r][c4 + 1] = v.y;
      tile[r][c4 + 2] = v.z; tile[r][c4 + 3] = v.w;
    }
  }
  __syncthreads();
  const int nl = t / 4, kb = (t % 4) * 16;
  bf16x8 o0, o1;
#pragma unroll
  for (int j = 0; j < 8; ++j) {
    o0[j] = (bf16)tile[kb + j][nl];
    o1[j] = (bf16)tile[kb + 8 + j][nl];
  }
  *(bf16x8*)&WT[(size_t)(n0 + nl) * 1024 + k0 + kb] = o0;
  *(bf16x8*)&WT[(size_t)(n0 + nl) * 1024 + k0 + kb + 8] = o1;
}

// ============== GEMM: C(16384 x N) = A(16384x1024) * BT(N x 1024)^T =========
// BM=BN=256, BK=64, 512 thr (8 waves 2Mx4N), per-wave C 128x64.
// LDS per buf: Alo[128][64] Ahi Blo Bhi (16KB slices); 2 bufs = 128KB.
// Swizzle: granule(elem bits 3..5) ^= row&7, on global src + ds_read.
template <int PROJ>
__global__ __launch_bounds__(512, 2) void gemm8(const bf16* __restrict__ A,
                                                const bf16* __restrict__ BT,
                                                bf16* __restrict__ Obf,
                                                float* __restrict__ Of,
                                                const int N, const int gy) {
  extern __shared__ bf16 lds[];  // 65536 elems = 128KB
  const int t = threadIdx.x;
  const int w = t >> 6, l = t & 63;
  // bijective XCD swizzle (grid % 8 == 0)
  const int nwg = (int)gridDim.x, cpx = nwg >> 3;
  const int f = ((int)blockIdx.x & 7) * cpx + ((int)blockIdx.x >> 3);
  const int bx = f / gy, by = f - bx * gy;
  const int m0 = bx * 256, n0 = by * 256;
  const int wm = (w >> 2) * 128, wn = (w & 3) * 64;
  const int lr = l & 15, lg = l >> 4;
  const int aslc = (w >> 2) * 8192;               // own A slice (in-buf elems)
  const int bslc = 16384 + ((w & 3) >> 1) * 8192; // own B slice
  const int brow = (w & 1) * 64;                  // row base within B slice
  // staging source coords. LDS row low-3 bits = (t>>3)&7; pre-swizzle source.
  const int srow = t >> 3;                                  // 0..63
  const int scol = ((t & 7) ^ ((t >> 3) & 7)) * 8;          // granule ^= row&7

  f32x4 acc[8][4] = {};
  bf16x8 av0[4], av1[4];  // phase-alternating A frags
  bf16x8 bv0[8], bv1[8];  // tile-alternating B frags

  // swizzled ds_read frag: slice-relative row sr, k-half ks.
  // granule bits (3..5 of elem col) = (ks*4+lg) ^ (sr&7).
#define FRAG(c, slc, sr_, ks_)                                          \
  (*(const bf16x8*)&lds[(c) * 32768 + (slc) + (sr_) * 64 +              \
                        (((ks_) * 32 + lg * 8) ^ (((sr_) & 7) << 3))])

#define STG(dbuf, slc, rbase, PTR, kt)                                        \
  do {                                                                        \
    const bf16* _s = (PTR) + (size_t)((rbase) + srow) * 1024 + (kt) * 64 + scol; \
    bf16* _d = lds + (dbuf) * 32768 + (slc) + w * 512;                        \
    gl_lds16(_s, _d);                                                         \
    gl_lds16(_s + 65536, _d + 4096);                                          \
  } while (0)

  // read the 4 A-frags of m-quadrant q from buffer c
#define RDA(dst, c, q)                                                        \
  _Pragma("unroll") for (int mi = 0; mi < 2; ++mi)                            \
    _Pragma("unroll") for (int kk = 0; kk < 2; ++kk)                          \
      dst[mi * 2 + kk] = FRAG(c, aslc, (q) * 32 + mi * 16 + lr, kk);

  // read the 8 B-frags (whole K-tile) from buffer c
#define RDB(dst, c)                                                           \
  _Pragma("unroll") for (int n = 0; n < 4; ++n)                               \
    _Pragma("unroll") for (int kk = 0; kk < 2; ++kk)                          \
      dst[n * 2 + kk] = FRAG(c, bslc, brow + n * 16 + lr, kk);

  // MFMA cluster for m-quadrant q using frag buffers av_, bv_
#define MM(q, av_, bv_)                                                       \
  __builtin_amdgcn_s_setprio(1);                                              \
  _Pragma("unroll") for (int mi = 0; mi < 2; ++mi)                            \
    _Pragma("unroll") for (int n = 0; n < 4; ++n)                             \
      _Pragma("unroll") for (int kk = 0; kk < 2; ++kk)                        \
        acc[(q) * 2 + mi][n] = __builtin_amdgcn_mfma_f32_16x16x32_bf16(       \
            av_[mi * 2 + kk], bv_[n * 2 + kk], acc[(q) * 2 + mi][n], 0, 0, 0);\
  __builtin_amdgcn_s_setprio(0);

  // prologue: A(0),B(0)->buf0; B(1)->buf1. vmcnt(4) confirms A(0)+B(0).
  STG(0, 0, m0, A, 0);        STG(0, 8192, m0 + 128, A, 0);
  STG(0, 16384, n0, BT, 0);   STG(0, 24576, n0 + 128, BT, 0);
  STG(1, 16384, n0, BT, 1);   STG(1, 24576, n0 + 128, BT, 1);
  VMCNT4();
  BAR();
  RDA(av0, 0, 0);
  RDB(bv0, 0);

#pragma unroll 1
  for (int I = 0; I < 8; ++I) {
    const int t2 = 2 * I;
    const int k1 = t2 + 1;                       // <= 15 always
    const int k2 = (t2 + 2 > 15) ? 15 : t2 + 2;  // dummy restage at tail
    const int k3 = (t2 + 3 > 15) ? 15 : t2 + 3;
    // ---- tile t2 (buf0), phases q=0..3; reads run ahead by one phase ----
    STG(1, 0, m0, A, k1);
    BAR(); RDA(av1, 0, 1); MM(0, av0, bv0); BAR();
    STG(1, 8192, m0 + 128, A, k1);
    BAR(); RDA(av0, 0, 2); MM(1, av1, bv0); BAR();
    STG(0, 16384, n0, BT, k2);
    BAR(); RDA(av1, 0, 3); MM(2, av0, bv0); BAR();
    STG(0, 24576, n0 + 128, BT, k2);
    VMCNT4();  // confirms A(t2+1)+B(t2+1) (newest 4 = B(t2+2) in flight)
    BAR(); RDA(av0, 1, 0); RDB(bv1, 1); MM(3, av1, bv0); BAR();
    // ---- tile t2+1 (buf1) ----
    STG(0, 0, m0, A, k2);
    BAR(); RDA(av1, 1, 1); MM(0, av0, bv1); BAR();
    STG(0, 8192, m0 + 128, A, k2);
    BAR(); RDA(av0, 1, 2); MM(1, av1, bv1); BAR();
    STG(1, 16384, n0, BT, k3);
    BAR(); RDA(av1, 1, 3); MM(2, av0, bv1); BAR();
    STG(1, 24576, n0 + 128, BT, k3);
    VMCNT4();  // confirms A(t2+2)+B(t2+2)
    BAR();
    if (I < 7) { RDA(av0, 0, 0); RDB(bv0, 0); }
    MM(3, av1, bv1);
    BAR();
  }
  VMCNT0();
#undef MM
#undef RDB
#undef RDA
#undef STG
#undef FRAG
  // ---- epilogue ----
#pragma unroll
  for (int m = 0; m < 8; ++m)
#pragma unroll
    for (int n = 0; n < 4; ++n)
#pragma unroll
      for (int r = 0; r < 4; ++r) {
        int row = m0 + wm + m * 16 + lg * 4 + r;
        int col = n0 + wn + n * 16 + lr;
        float v = acc[m][n][r];
        if (PROJ) {
          if (col < 2048) v = fmact(v);
          Obf[(size_t)row * N + col] = (bf16)v;
        } else {
          Of[(size_t)row * N + col] = v;
        }
      }
}

// ---------------- Pass B: per-chunk S_c^T = (K_c^T V_c)^T (64x64), z_c ------
__global__ __launch_bounds__(256) void chunk_ktv(const bf16* __restrict__ QKV,
                                                 float* __restrict__ S_ws,
                                                 float* __restrict__ z_ws) {
  const int blk = blockIdx.x;  // bh*32 + c
  const int bh = blk >> 5, c = blk & 31;
  const int b = bh >> 4, h = bh & 15;
  const size_t rowbase = (size_t)b * 4096 + (size_t)c * 128;
  __shared__ alignas(16) bf16 KT[64 * 136];
  __shared__ alignas(16) bf16 VT[64 * 136];
  __shared__ float zpart[4][64];
  const int t = threadIdx.x;
  {
    const int r = t >> 1, c0 = (t & 1) * 32;
    const bf16* kp = QKV + (rowbase + r) * 3072 + 1024 + h * 64 + c0;
    const bf16* vp = QKV + (rowbase + r) * 3072 + 2048 + h * 64 + c0;
    bf16x8 kv[4], vv[4];
#pragma unroll
    for (int q8 = 0; q8 < 4; ++q8) {
      kv[q8] = *(const bf16x8*)&kp[q8 * 8];
      vv[q8] = *(const bf16x8*)&vp[q8 * 8];
    }
#pragma unroll
    for (int q8 = 0; q8 < 4; ++q8)
#pragma unroll
      for (int j = 0; j < 8; ++j) {
        KT[(c0 + q8 * 8 + j) * 136 + r] = kv[q8][j];
        VT[(c0 + q8 * 8 + j) * 136 + r] = vv[q8][j];
      }
  }
  __syncthreads();
  {  // z[d] = sum_t K[t][d], 4-way parallel over row quarters
    const int d = t & 63, part = t >> 6;
    float zs = 0.f;
#pragma unroll
    for (int tt = 0; tt < 32; ++tt) zs += (float)KT[d * 136 + part * 32 + tt];
    zpart[part][d] = zs;
  }
  __syncthreads();
  if (t < 64)
    z_ws[(size_t)blk * 64 + t] =
        zpart[0][t] + zpart[1][t] + zpart[2][t] + zpart[3][t];
  const int l = t & 63, w = t >> 6;
  const int lr = l & 15, lg = l >> 4, lk = lg * 8;
  f32x4 acc[4] = {};
  // S^T[e][d]: A = V^T rows (e), B = K^T rows (d)
#pragma unroll
  for (int ks = 0; ks < 4; ++ks) {
    const int k0 = ks * 32;
    bf16x8 a = *(const bf16x8*)&VT[(w * 16 + lr) * 136 + k0 + lk];
#pragma unroll
    for (int n = 0; n < 4; ++n) {
      bf16x8 bk = *(const bf16x8*)&KT[(n * 16 + lr) * 136 + k0 + lk];
      acc[n] = __builtin_amdgcn_mfma_f32_16x16x32_bf16(a, bk, acc[n], 0, 0, 0);
    }
  }
#pragma unroll
  for (int n = 0; n < 4; ++n)
#pragma unroll
    for (int r = 0; r < 4; ++r) {
      int e = w * 16 + lg * 4 + r;
      int d = n * 16 + lr;
      S_ws[((size_t)blk * 64 + e) * 64 + d] = acc[n][r];
    }
}

// -------- Pass B2: exclusive prefix over chunks (register scan, prefetched) --
__global__ __launch_bounds__(256) void prefix_scan(const float* __restrict__ S_ws,
                                                   const float* __restrict__ z_ws,
                                                   bf16* __restrict__ STp,
                                                   float* __restrict__ zP) {
  const int bh = blockIdx.x >> 2, dq = blockIdx.x & 3;
  const int t = threadIdx.x;
  const int e = t >> 2, d0 = dq * 16 + (t & 3) * 4;
  float r0 = 0.f, r1 = 0.f, r2 = 0.f, r3 = 0.f, zr = 0.f;
  const bool doz = (dq == 0) && (t < 64);
  const size_t base = (size_t)bh * 32;
  float4 v = *(const float4*)&S_ws[base * 4096 + e * 64 + d0];
  float zv = doz ? z_ws[base * 64 + t] : 0.f;
  for (int c = 0; c < 32; ++c) {
    float4 vn = {0.f, 0.f, 0.f, 0.f};
    float zn = 0.f;
    if (c < 31) {
      vn = *(const float4*)&S_ws[(base + c + 1) * 4096 + e * 64 + d0];
      if (doz) zn = z_ws[(base + c + 1) * 64 + t];
    }
    const size_t cb = base + c;
    bf16x4 o;
    o[0] = (bf16)r0; o[1] = (bf16)r1; o[2] = (bf16)r2; o[3] = (bf16)r3;
    *(bf16x4*)&STp[cb * 4096 + e * 64 + d0] = o;
    if (doz) zP[cb * 64 + t] = zr;
    r0 += v.x; r1 += v.y; r2 += v.z; r3 += v.w;
    zr += zv;
    v = vn; zv = zn;
  }
}

// -------- Pass C: per-chunk attention output ---------------------------------
__global__ __launch_bounds__(256) void chunk_attn(const bf16* __restrict__ QKV,
                                                  const bf16* __restrict__ STp,
                                                  const float* __restrict__ zP,
                                                  bf16* __restrict__ Y) {
  const int blk = blockIdx.x;
  const int bh = blk >> 5, c = blk & 31;
  const int b = bh >> 4, h = bh & 15;
  const size_t cb = (size_t)bh * 32 + c;
  const size_t rowbase = (size_t)b * 4096 + (size_t)c * 128;
  const bf16* Q = QKV + rowbase * 3072 + h * 64;
  const bf16* K = QKV + rowbase * 3072 + 1024 + h * 64;
  const bf16* V = QKV + rowbase * 3072 + 2048 + h * 64;
  __shared__ alignas(16) bf16 VT[64 * 136];
  __shared__ alignas(16) bf16 P[128 * 136];
  __shared__ float den[128];
  const int t = threadIdx.x;
  {  // stage V^T in LDS
    const int r = t >> 1, c0 = (t & 1) * 32;
    const bf16* vp = V + (size_t)r * 3072 + c0;
    bf16x8 vv[4];
#pragma unroll
    for (int q8 = 0; q8 < 4; ++q8) vv[q8] = *(const bf16x8*)&vp[q8 * 8];
#pragma unroll
    for (int q8 = 0; q8 < 4; ++q8)
#pragma unroll
      for (int j = 0; j < 8; ++j) VT[(c0 + q8 * 8 + j) * 136 + r] = vv[q8][j];
  }
  const int l = t & 63, w = t >> 6;
  const int lr = l & 15, lg = l >> 4, lk = lg * 8;
  f32x4 acc[2][4] = {};
  f32x4 accs[2][8] = {};
#pragma unroll
  for (int kq = 0; kq < 2; ++kq) {
    const int k0 = kq * 32;
    bf16x8 am[2];
#pragma unroll
    for (int m = 0; m < 2; ++m)
      am[m] = *(const bf16x8*)&Q[(size_t)(w * 32 + m * 16 + lr) * 3072 + k0 + lk];
#pragma unroll
    for (int n = 0; n < 4; ++n) {  // inter: Q @ S_prev
      bf16x8 bs = *(const bf16x8*)&STp[cb * 4096 + (size_t)(n * 16 + lr) * 64 + k0 + lk];
#pragma unroll
      for (int m = 0; m < 2; ++m)
        acc[m][n] = __builtin_amdgcn_mfma_f32_16x16x32_bf16(am[m], bs, acc[m][n], 0, 0, 0);
    }
#pragma unroll
    for (int n = 0; n < 8; ++n) {  // intra scores: Q @ K^T
      bf16x8 bk = *(const bf16x8*)&K[(size_t)(n * 16 + lr) * 3072 + k0 + lk];
#pragma unroll
      for (int m = 0; m < 2; ++m)
        accs[m][n] = __builtin_amdgcn_mfma_f32_16x16x32_bf16(am[m], bk, accs[m][n], 0, 0, 0);
    }
  }
#pragma unroll
  for (int m = 0; m < 2; ++m)
#pragma unroll
    for (int r = 0; r < 4; ++r) {
      const int row_c = w * 32 + m * 16 + lg * 4 + r;
      float s = 0.f;
#pragma unroll
      for (int n = 0; n < 8; ++n) {
        const int col_c = n * 16 + lr;
        float v = accs[m][n][r];
        v = (col_c <= row_c) ? v : 0.f;
        accs[m][n][r] = v;
        s += v;
      }
      s += __shfl_xor(s, 1);
      s += __shfl_xor(s, 2);
      s += __shfl_xor(s, 4);
      s += __shfl_xor(s, 8);
      if (lr == 0) den[row_c] = s;
#pragma unroll
      for (int n = 0; n < 8; ++n)
        P[row_c * 136 + n * 16 + lr] = (bf16)accs[m][n][r];
    }
  __syncthreads();
  if (t < 128) {
    float s = EPS;
    const bf16* qr = Q + (size_t)t * 3072;
    const float* zp = zP + cb * 64;
#pragma unroll
    for (int d8 = 0; d8 < 64; d8 += 8) {
      bf16x8 qv = *(const bf16x8*)&qr[d8];
#pragma unroll
      for (int j = 0; j < 8; ++j) s += (float)qv[j] * zp[d8 + j];
    }
    den[t] += s;
  }
#pragma unroll
  for (int ks = 0; ks < 4; ++ks) {
    const int k0 = ks * 32;
    bf16x8 ap[2];
#pragma unroll
    for (int m = 0; m < 2; ++m)
      ap[m] = *(const bf16x8*)&P[(w * 32 + m * 16 + lr) * 136 + k0 + lk];
#pragma unroll
    for (int n = 0; n < 4; ++n) {
      bf16x8 bv = *(const bf16x8*)&VT[(n * 16 + lr) * 136 + k0 + lk];
#pragma unroll
      for (int m = 0; m < 2; ++m)
        acc[m][n] = __builtin_amdgcn_mfma_f32_16x16x32_bf16(ap[m], bv, acc[m][n], 0, 0, 0);
    }
  }
  __syncthreads();
#pragma unroll
  for (int m = 0; m < 2; ++m)
#pragma unroll
    for (int n = 0; n < 4; ++n)
#pragma unroll
      for (int r = 0; r < 4; ++r) {
        const int row_c = w * 32 + m * 16 + lg * 4 + r;
        const int col = n * 16 + lr;
        float y = acc[m][n][r] / den[row_c];
        Y[(rowbase + row_c) * 1024 + h * 64 + col] = (bf16)y;
      }
}

extern "C" void kernel_launch(void* const* d_in, const int* in_sizes, int n_in,
                              void* d_out, int out_size, void* d_ws, size_t ws_size,
                              hipStream_t stream) {
  (void)in_sizes; (void)n_in; (void)out_size; (void)ws_size;
  const float* x  = (const float*)d_in[0];
  const float* Wq = (const float*)d_in[1];
  const float* Wk = (const float*)d_in[2];
  const float* Wv = (const float*)d_in[3];
  const float* Wo = (const float*)d_in[4];
  char* ws = (char*)d_ws;
  bf16*  XB   = (bf16*)ws;                    // 33,554,432 (x bf16; reused as Y)
  bf16*  WT3  = (bf16*)(ws + 33554432);       //  6,291,456 (WqT|WkT|WvT)
  bf16*  WOT  = (bf16*)(ws + 39845888);       //  2,097,152 (WoT)
  bf16*  QKV  = (bf16*)(ws + 41943040);       // 100,663,296 (16384x3072)
  float* S_ws = (float*)(ws + 142606336);     // 33,554,432 (S^T per chunk)
  float* z_ws = (float*)(ws + 176160768);     //    524,288
  bf16*  STp  = (bf16*)(ws + 176685056);      // 16,777,216
  float* zP   = (float*)(ws + 193462272);     //    524,288
  bf16*  Y    = XB;

  {
    auto k1 = gemm8<1>; auto k0 = gemm8<0>;
    (void)hipFuncSetAttribute((const void*)k1,
        hipFuncAttributeMaxDynamicSharedMemorySize, 131072);
    (void)hipFuncSetAttribute((const void*)k0,
        hipFuncAttributeMaxDynamicSharedMemorySize, 131072);
  }

  prep<<<9216, 256, 0, stream>>>(x, Wq, Wk, Wv, Wo, XB, WT3, WOT);
  gemm8<1><<<768, 512, 131072, stream>>>(XB, WT3, QKV, nullptr, 3072, 12);
  chunk_ktv<<<2048, 256, 0, stream>>>(QKV, S_ws, z_ws);
  prefix_scan<<<256, 256, 0, stream>>>(S_ws, z_ws, STp, zP);
  chunk_attn<<<2048, 256, 0, stream>>>(QKV, STp, zP, Y);
  gemm8<0><<<256, 512, 131072, stream>>>(Y, WOT, nullptr, (float*)d_out, 1024, 4);
}

// Round 8
// 263.720 us; speedup vs baseline: 1.0352x; 1.0352x over previous
//
#include <hip/hip_runtime.h>

// LinearAttention: x(B,T,D) -> QKV proj -> ELU+1 -> chunked causal linear
// attention -> output proj. B=4 T=4096 D=1024 H=16 HD=64.
// R8: R6 GEMM (R7 reg-pipeline reverted: VGPR cap forced scratch spill) with
// ONE barrier per phase instead of two. Safety re-verified: reads(p) drain at
// lgkmcnt(0) before MFMA(p) -> before end-of-phase barrier -> stage(p+1)
// (issued post-barrier) can never overwrite a slice still being read; within-
// phase stage targets disjoint from read slices (all 8 phases checked);
// vmcnt(4) before the end barrier keeps staged-data visibility.

typedef __bf16 bf16;
typedef __bf16 bf16x4 __attribute__((ext_vector_type(4)));
typedef __bf16 bf16x8 __attribute__((ext_vector_type(8)));
typedef float f32x4 __attribute__((ext_vector_type(4)));

#define EPS 1e-6f

#define BAR() asm volatile("s_barrier" ::: "memory")
#define VMCNT4() asm volatile("s_waitcnt vmcnt(4)" ::: "memory")
#define VMCNT0() asm volatile("s_waitcnt vmcnt(0)" ::: "memory")

__device__ __forceinline__ void gl_lds16(const void* g, void* l) {
  __builtin_amdgcn_global_load_lds(
      (__attribute__((address_space(1))) void*)g,
      (__attribute__((address_space(3))) void*)l, 16, 0, 0);
}

__device__ __forceinline__ float fmact(float v) {
  return v > 0.f ? v + 1.f : __expf(v);  // elu+1
}

// ------------- prep: x f32->bf16 (blocks 0..8191) + 4x W transpose ----------
__global__ __launch_bounds__(256) void prep(const float* __restrict__ x,
                                            const float* __restrict__ Wq,
                                            const float* __restrict__ Wk,
                                            const float* __restrict__ Wv,
                                            const float* __restrict__ Wo,
                                            bf16* __restrict__ XB,
                                            bf16* __restrict__ WT3,
                                            bf16* __restrict__ WOT) {
  const int bid = blockIdx.x;
  const int t = threadIdx.x;
  if (bid < 8192) {  // x convert: 8192*256*8 = 16,777,216 elems exactly
    size_t base = ((size_t)bid * 256 + t) * 8;
    float4 v0 = *(const float4*)&x[base];
    float4 v1 = *(const float4*)&x[base + 4];
    bf16x8 o;
    o[0] = (bf16)v0.x; o[1] = (bf16)v0.y; o[2] = (bf16)v0.z; o[3] = (bf16)v0.w;
    o[4] = (bf16)v1.x; o[5] = (bf16)v1.y; o[6] = (bf16)v1.z; o[7] = (bf16)v1.w;
    *(bf16x8*)&XB[base] = o;
    return;
  }
  // weight transpose: W (K x N f32) -> WT (N x K bf16), 64x64 tiles
  __shared__ float tile[64][65];
  const int wi = (bid - 8192) >> 8;     // 0..3
  const int local = (bid - 8192) & 255;
  const float* W = (wi == 0) ? Wq : (wi == 1) ? Wk : (wi == 2) ? Wv : Wo;
  bf16* WT = (wi == 3) ? WOT : WT3 + (size_t)wi * 1048576;
  const int k0 = (local & 15) * 64, n0 = (local >> 4) * 64;
  {
    const int r4 = t / 16, c4 = (t % 16) * 4;
#pragma unroll
    for (int rr = 0; rr < 4; ++rr) {
      int r = r4 + rr * 16;
      float4 v = *(const float4*)&W[(size_t)(k0 + r) * 1024 + n0 + c4];
      tile[r][c4] = v.x; tile[r][c4 + 1] = v.y;
      tile[r][c4 + 2] = v.z; tile[r][c4 + 3] = v.w;
    }
  }
  __syncthreads();
  const int nl = t / 4, kb = (t % 4) * 16;
  bf16x8 o0, o1;
#pragma unroll
  for (int j = 0; j < 8; ++j) {
    o0[j] = (bf16)tile[kb + j][nl];
    o1[j] = (bf16)tile[kb + 8 + j][nl];
  }
  *(bf16x8*)&WT[(size_t)(n0 + nl) * 1024 + k0 + kb] = o0;
  *(bf16x8*)&WT[(size_t)(n0 + nl) * 1024 + k0 + kb + 8] = o1;
}

// ============== GEMM: C(16384 x N) = A(16384x1024) * BT(N x 1024)^T =========
// BM=BN=256, BK=64, 512 thr (8 waves 2Mx4N), per-wave C 128x64.
// LDS per buf: Alo[128][64] Ahi Blo Bhi (16KB slices); 2 bufs = 128KB.
// Swizzle: granule(elem bits 3..5) ^= row&7, on global src + ds_read.
// ONE barrier per phase (end), reads+MFMA share the region.
template <int PROJ>
__global__ __launch_bounds__(512, 2) void gemm8(const bf16* __restrict__ A,
                                                const bf16* __restrict__ BT,
                                                bf16* __restrict__ Obf,
                                                float* __restrict__ Of,
                                                const int N, const int gy) {
  extern __shared__ bf16 lds[];  // 65536 elems = 128KB
  const int t = threadIdx.x;
  const int w = t >> 6, l = t & 63;
  // bijective XCD swizzle (grid % 8 == 0)
  const int nwg = (int)gridDim.x, cpx = nwg >> 3;
  const int f = ((int)blockIdx.x & 7) * cpx + ((int)blockIdx.x >> 3);
  const int bx = f / gy, by = f - bx * gy;
  const int m0 = bx * 256, n0 = by * 256;
  const int wm = (w >> 2) * 128, wn = (w & 3) * 64;
  const int lr = l & 15, lg = l >> 4;
  const int aslc = (w >> 2) * 8192;               // own A slice (in-buf elems)
  const int bslc = 16384 + ((w & 3) >> 1) * 8192; // own B slice
  const int brow = (w & 1) * 64;                  // row base within B slice
  // staging source coords. LDS row low-3 bits = (t>>3)&7; pre-swizzle source.
  const int srow = t >> 3;                                  // 0..63
  const int scol = ((t & 7) ^ ((t >> 3) & 7)) * 8;          // granule ^= row&7

  f32x4 acc[8][4] = {};
  bf16x8 bv[8];

  // swizzled ds_read frag: slice-relative row sr, k-half ks.
  // granule bits (3..5 of elem col) = (ks*4+lg) ^ (sr&7).
#define FRAG(c, slc, sr_, ks_)                                          \
  (*(const bf16x8*)&lds[(c) * 32768 + (slc) + (sr_) * 64 +              \
                        (((ks_) * 32 + lg * 8) ^ (((sr_) & 7) << 3))])

#define STG(dbuf, slc, rbase, PTR, kt)                                        \
  do {                                                                        \
    const bf16* _s = (PTR) + (size_t)((rbase) + srow) * 1024 + (kt) * 64 + scol; \
    bf16* _d = lds + (dbuf) * 32768 + (slc) + w * 512;                        \
    gl_lds16(_s, _d);                                                         \
    gl_lds16(_s + 65536, _d + 4096);                                          \
  } while (0)

  // phase: reads -> stage -> (vmcnt) -> MFMA -> ONE barrier
#define PHASE(c, q, STAGE_STMT, VM)                                           \
  {                                                                           \
    bf16x8 av[4];                                                             \
    _Pragma("unroll") for (int mi = 0; mi < 2; ++mi)                          \
      _Pragma("unroll") for (int kk = 0; kk < 2; ++kk)                        \
        av[mi * 2 + kk] = FRAG(c, aslc, (q) * 32 + mi * 16 + lr, kk);         \
    if ((q) == 0) {                                                           \
      _Pragma("unroll") for (int n = 0; n < 4; ++n)                           \
        _Pragma("unroll") for (int kk = 0; kk < 2; ++kk)                      \
          bv[n * 2 + kk] = FRAG(c, bslc, brow + n * 16 + lr, kk);             \
    }                                                                         \
    STAGE_STMT;                                                               \
    if (VM) VMCNT4();                                                         \
    __builtin_amdgcn_s_setprio(1);                                            \
    _Pragma("unroll") for (int mi = 0; mi < 2; ++mi)                          \
      _Pragma("unroll") for (int n = 0; n < 4; ++n)                           \
        _Pragma("unroll") for (int kk = 0; kk < 2; ++kk)                      \
          acc[(q) * 2 + mi][n] = __builtin_amdgcn_mfma_f32_16x16x32_bf16(     \
              av[mi * 2 + kk], bv[n * 2 + kk], acc[(q) * 2 + mi][n], 0, 0, 0);\
    __builtin_amdgcn_s_setprio(0);                                            \
    BAR();                                                                    \
  }

  // prologue: A(0),B(0)->buf0; B(1)->buf1. vmcnt(4) confirms A(0)+B(0).
  STG(0, 0, m0, A, 0);        STG(0, 8192, m0 + 128, A, 0);
  STG(0, 16384, n0, BT, 0);   STG(0, 24576, n0 + 128, BT, 0);
  STG(1, 16384, n0, BT, 1);   STG(1, 24576, n0 + 128, BT, 1);
  VMCNT4();
  BAR();

#pragma unroll 1
  for (int I = 0; I < 8; ++I) {
    const int t2 = 2 * I;
    const int k1 = t2 + 1;                       // <= 15 always
    const int k2 = (t2 + 2 > 15) ? 15 : t2 + 2;  // dummy restage at tail
    const int k3 = (t2 + 3 > 15) ? 15 : t2 + 3;
    PHASE(0, 0, STG(1, 0, m0, A, k1), 0);             // p1 + stage Alo(t+1)
    PHASE(0, 1, STG(1, 8192, m0 + 128, A, k1), 0);    // p2 + Ahi(t+1)
    PHASE(0, 2, STG(0, 16384, n0, BT, k2), 0);        // p3 + Blo(t+2)
    PHASE(0, 3, STG(0, 24576, n0 + 128, BT, k2), 1);  // p4 + Bhi(t+2), vmcnt
    PHASE(1, 0, STG(0, 0, m0, A, k2), 0);             // p5 + Alo(t+2)
    PHASE(1, 1, STG(0, 8192, m0 + 128, A, k2), 0);    // p6 + Ahi(t+2)
    PHASE(1, 2, STG(1, 16384, n0, BT, k3), 0);        // p7 + Blo(t+3)
    PHASE(1, 3, STG(1, 24576, n0 + 128, BT, k3), 1);  // p8 + Bhi(t+3), vmcnt
  }
  VMCNT0();
#undef PHASE
#undef STG
#undef FRAG
  // ---- epilogue ----
#pragma unroll
  for (int m = 0; m < 8; ++m)
#pragma unroll
    for (int n = 0; n < 4; ++n)
#pragma unroll
      for (int r = 0; r < 4; ++r) {
        int row = m0 + wm + m * 16 + lg * 4 + r;
        int col = n0 + wn + n * 16 + lr;
        float v = acc[m][n][r];
        if (PROJ) {
          if (col < 2048) v = fmact(v);
          Obf[(size_t)row * N + col] = (bf16)v;
        } else {
          Of[(size_t)row * N + col] = v;
        }
      }
}

// ---------------- Pass B: per-chunk S_c^T = (K_c^T V_c)^T (64x64), z_c ------
__global__ __launch_bounds__(256) void chunk_ktv(const bf16* __restrict__ QKV,
                                                 float* __restrict__ S_ws,
                                                 float* __restrict__ z_ws) {
  const int blk = blockIdx.x;  // bh*32 + c
  const int bh = blk >> 5, c = blk & 31;
  const int b = bh >> 4, h = bh & 15;
  const size_t rowbase = (size_t)b * 4096 + (size_t)c * 128;
  __shared__ alignas(16) bf16 KT[64 * 136];
  __shared__ alignas(16) bf16 VT[64 * 136];
  __shared__ float zpart[4][64];
  const int t = threadIdx.x;
  {
    const int r = t >> 1, c0 = (t & 1) * 32;
    const bf16* kp = QKV + (rowbase + r) * 3072 + 1024 + h * 64 + c0;
    const bf16* vp = QKV + (rowbase + r) * 3072 + 2048 + h * 64 + c0;
    bf16x8 kv[4], vv[4];
#pragma unroll
    for (int q8 = 0; q8 < 4; ++q8) {
      kv[q8] = *(const bf16x8*)&kp[q8 * 8];
      vv[q8] = *(const bf16x8*)&vp[q8 * 8];
    }
#pragma unroll
    for (int q8 = 0; q8 < 4; ++q8)
#pragma unroll
      for (int j = 0; j < 8; ++j) {
        KT[(c0 + q8 * 8 + j) * 136 + r] = kv[q8][j];
        VT[(c0 + q8 * 8 + j) * 136 + r] = vv[q8][j];
      }
  }
  __syncthreads();
  {  // z[d] = sum_t K[t][d], 4-way parallel over row quarters
    const int d = t & 63, part = t >> 6;
    float zs = 0.f;
#pragma unroll
    for (int tt = 0; tt < 32; ++tt) zs += (float)KT[d * 136 + part * 32 + tt];
    zpart[part][d] = zs;
  }
  __syncthreads();
  if (t < 64)
    z_ws[(size_t)blk * 64 + t] =
        zpart[0][t] + zpart[1][t] + zpart[2][t] + zpart[3][t];
  const int l = t & 63, w = t >> 6;
  const int lr = l & 15, lg = l >> 4, lk = lg * 8;
  f32x4 acc[4] = {};
  // S^T[e][d]: A = V^T rows (e), B = K^T rows (d)
#pragma unroll
  for (int ks = 0; ks < 4; ++ks) {
    const int k0 = ks * 32;
    bf16x8 a = *(const bf16x8*)&VT[(w * 16 + lr) * 136 + k0 + lk];
#pragma unroll
    for (int n = 0; n < 4; ++n) {
      bf16x8 bk = *(const bf16x8*)&KT[(n * 16 + lr) * 136 + k0 + lk];
      acc[n] = __builtin_amdgcn_mfma_f32_16x16x32_bf16(a, bk, acc[n], 0, 0, 0);
    }
  }
#pragma unroll
  for (int n = 0; n < 4; ++n)
#pragma unroll
    for (int r = 0; r < 4; ++r) {
      int e = w * 16 + lg * 4 + r;
      int d = n * 16 + lr;
      S_ws[((size_t)blk * 64 + e) * 64 + d] = acc[n][r];
    }
}

// -------- Pass B2: exclusive prefix over chunks (register scan, prefetched) --
__global__ __launch_bounds__(256) void prefix_scan(const float* __restrict__ S_ws,
                                                   const float* __restrict__ z_ws,
                                                   bf16* __restrict__ STp,
                                                   float* __restrict__ zP) {
  const int bh = blockIdx.x >> 2, dq = blockIdx.x & 3;
  const int t = threadIdx.x;
  const int e = t >> 2, d0 = dq * 16 + (t & 3) * 4;
  float r0 = 0.f, r1 = 0.f, r2 = 0.f, r3 = 0.f, zr = 0.f;
  const bool doz = (dq == 0) && (t < 64);
  const size_t base = (size_t)bh * 32;
  float4 v = *(const float4*)&S_ws[base * 4096 + e * 64 + d0];
  float zv = doz ? z_ws[base * 64 + t] : 0.f;
  for (int c = 0; c < 32; ++c) {
    float4 vn = {0.f, 0.f, 0.f, 0.f};
    float zn = 0.f;
    if (c < 31) {
      vn = *(const float4*)&S_ws[(base + c + 1) * 4096 + e * 64 + d0];
      if (doz) zn = z_ws[(base + c + 1) * 64 + t];
    }
    const size_t cb = base + c;
    bf16x4 o;
    o[0] = (bf16)r0; o[1] = (bf16)r1; o[2] = (bf16)r2; o[3] = (bf16)r3;
    *(bf16x4*)&STp[cb * 4096 + e * 64 + d0] = o;
    if (doz) zP[cb * 64 + t] = zr;
    r0 += v.x; r1 += v.y; r2 += v.z; r3 += v.w;
    zr += zv;
    v = vn; zv = zn;
  }
}

// -------- Pass C: per-chunk attention output ---------------------------------
__global__ __launch_bounds__(256) void chunk_attn(const bf16* __restrict__ QKV,
                                                  const bf16* __restrict__ STp,
                                                  const float* __restrict__ zP,
                                                  bf16* __restrict__ Y) {
  const int blk = blockIdx.x;
  const int bh = blk >> 5, c = blk & 31;
  const int b = bh >> 4, h = bh & 15;
  const size_t cb = (size_t)bh * 32 + c;
  const size_t rowbase = (size_t)b * 4096 + (size_t)c * 128;
  const bf16* Q = QKV + rowbase * 3072 + h * 64;
  const bf16* K = QKV + rowbase * 3072 + 1024 + h * 64;
  const bf16* V = QKV + rowbase * 3072 + 2048 + h * 64;
  __shared__ alignas(16) bf16 VT[64 * 136];
  __shared__ alignas(16) bf16 P[128 * 136];
  __shared__ float den[128];
  const int t = threadIdx.x;
  {  // stage V^T in LDS
    const int r = t >> 1, c0 = (t & 1) * 32;
    const bf16* vp = V + (size_t)r * 3072 + c0;
    bf16x8 vv[4];
#pragma unroll
    for (int q8 = 0; q8 < 4; ++q8) vv[q8] = *(const bf16x8*)&vp[q8 * 8];
#pragma unroll
    for (int q8 = 0; q8 < 4; ++q8)
#pragma unroll
      for (int j = 0; j < 8; ++j) VT[(c0 + q8 * 8 + j) * 136 + r] = vv[q8][j];
  }
  const int l = t & 63, w = t >> 6;
  const int lr = l & 15, lg = l >> 4, lk = lg * 8;
  f32x4 acc[2][4] = {};
  f32x4 accs[2][8] = {};
#pragma unroll
  for (int kq = 0; kq < 2; ++kq) {
    const int k0 = kq * 32;
    bf16x8 am[2];
#pragma unroll
    for (int m = 0; m < 2; ++m)
      am[m] = *(const bf16x8*)&Q[(size_t)(w * 32 + m * 16 + lr) * 3072 + k0 + lk];
#pragma unroll
    for (int n = 0; n < 4; ++n) {  // inter: Q @ S_prev
      bf16x8 bs = *(const bf16x8*)&STp[cb * 4096 + (size_t)(n * 16 + lr) * 64 + k0 + lk];
#pragma unroll
      for (int m = 0; m < 2; ++m)
        acc[m][n] = __builtin_amdgcn_mfma_f32_16x16x32_bf16(am[m], bs, acc[m][n], 0, 0, 0);
    }
#pragma unroll
    for (int n = 0; n < 8; ++n) {  // intra scores: Q @ K^T
      bf16x8 bk = *(const bf16x8*)&K[(size_t)(n * 16 + lr) * 3072 + k0 + lk];
#pragma unroll
      for (int m = 0; m < 2; ++m)
        accs[m][n] = __builtin_amdgcn_mfma_f32_16x16x32_bf16(am[m], bk, accs[m][n], 0, 0, 0);
    }
  }
#pragma unroll
  for (int m = 0; m < 2; ++m)
#pragma unroll
    for (int r = 0; r < 4; ++r) {
      const int row_c = w * 32 + m * 16 + lg * 4 + r;
      float s = 0.f;
#pragma unroll
      for (int n = 0; n < 8; ++n) {
        const int col_c = n * 16 + lr;
        float v = accs[m][n][r];
        v = (col_c <= row_c) ? v : 0.f;
        accs[m][n][r] = v;
        s += v;
      }
      s += __shfl_xor(s, 1);
      s += __shfl_xor(s, 2);
      s += __shfl_xor(s, 4);
      s += __shfl_xor(s, 8);
      if (lr == 0) den[row_c] = s;
#pragma unroll
      for (int n = 0; n < 8; ++n)
        P[row_c * 136 + n * 16 + lr] = (bf16)accs[m][n][r];
    }
  __syncthreads();
  if (t < 128) {
    float s = EPS;
    const bf16* qr = Q + (size_t)t * 3072;
    const float* zp = zP + cb * 64;
#pragma unroll
    for (int d8 = 0; d8 < 64; d8 += 8) {
      bf16x8 qv = *(const bf16x8*)&qr[d8];
#pragma unroll
      for (int j = 0; j < 8; ++j) s += (float)qv[j] * zp[d8 + j];
    }
    den[t] += s;
  }
#pragma unroll
  for (int ks = 0; ks < 4; ++ks) {
    const int k0 = ks * 32;
    bf16x8 ap[2];
#pragma unroll
    for (int m = 0; m < 2; ++m)
      ap[m] = *(const bf16x8*)&P[(w * 32 + m * 16 + lr) * 136 + k0 + lk];
#pragma unroll
    for (int n = 0; n < 4; ++n) {
      bf16x8 bv = *(const bf16x8*)&VT[(n * 16 + lr) * 136 + k0 + lk];
#pragma unroll
      for (int m = 0; m < 2; ++m)
        acc[m][n] = __builtin_amdgcn_mfma_f32_16x16x32_bf16(ap[m], bv, acc[m][n], 0, 0, 0);
    }
  }
  __syncthreads();
#pragma unroll
  for (int m = 0; m < 2; ++m)
#pragma unroll
    for (int n = 0; n < 4; ++n)
#pragma unroll
      for (int r = 0; r < 4; ++r) {
        const int row_c = w * 32 + m * 16 + lg * 4 + r;
        const int col = n * 16 + lr;
        float y = acc[m][n][r] / den[row_c];
        Y[(rowbase + row_c) * 1024 + h * 64 + col] = (bf16)y;
      }
}

extern "C" void kernel_launch(void* const* d_in, const int* in_sizes, int n_in,
                              void* d_out, int out_size, void* d_ws, size_t ws_size,
                              hipStream_t stream) {
  (void)in_sizes; (void)n_in; (void)out_size; (void)ws_size;
  const float* x  = (const float*)d_in[0];
  const float* Wq = (const float*)d_in[1];
  const float* Wk = (const float*)d_in[2];
  const float* Wv = (const float*)d_in[3];
  const float* Wo = (const float*)d_in[4];
  char* ws = (char*)d_ws;
  bf16*  XB   = (bf16*)ws;                    // 33,554,432 (x bf16; reused as Y)
  bf16*  WT3  = (bf16*)(ws + 33554432);       //  6,291,456 (WqT|WkT|WvT)
  bf16*  WOT  = (bf16*)(ws + 39845888);       //  2,097,152 (WoT)
  bf16*  QKV  = (bf16*)(ws + 41943040);       // 100,663,296 (16384x3072)
  float* S_ws = (float*)(ws + 142606336);     // 33,554,432 (S^T per chunk)
  float* z_ws = (float*)(ws + 176160768);     //    524,288
  bf16*  STp  = (bf16*)(ws + 176685056);      // 16,777,216
  float* zP   = (float*)(ws + 193462272);     //    524,288
  bf16*  Y    = XB;

  {
    auto k1 = gemm8<1>; auto k0 = gemm8<0>;
    (void)hipFuncSetAttribute((const void*)k1,
        hipFuncAttributeMaxDynamicSharedMemorySize, 131072);
    (void)hipFuncSetAttribute((const void*)k0,
        hipFuncAttributeMaxDynamicSharedMemorySize, 131072);
  }

  prep<<<9216, 256, 0, stream>>>(x, Wq, Wk, Wv, Wo, XB, WT3, WOT);
  gemm8<1><<<768, 512, 131072, stream>>>(XB, WT3, QKV, nullptr, 3072, 12);
  chunk_ktv<<<2048, 256, 0, stream>>>(QKV, S_ws, z_ws);
  prefix_scan<<<256, 256, 0, stream>>>(S_ws, z_ws, STp, zP);
  chunk_attn<<<2048, 256, 0, stream>>>(QKV, STp, zP, Y);
  gemm8<0><<<256, 512, 131072, stream>>>(Y, WOT, nullptr, (float*)d_out, 1024, 4);
}